// Round 19
// baseline (697.901 us; speedup 1.0000x reference)
//
#include <hip/hip_runtime.h>
#include <math.h>

typedef float f32x4 __attribute__((ext_vector_type(4)));
typedef short bf16x8 __attribute__((ext_vector_type(8)));
typedef unsigned short u16;
typedef unsigned int u32;
typedef unsigned long long u64;

#define FLAG_STRIDE 16            // one u32 flag per 64B line
// step flags: [t=128][j=64][wavepart=4] = 32768 lines
#define ACQ_BASE    32768         // 256 acquire-dummy lines
#define EPOCH_BASE  33024         // 64 epoch lines
#define QCNT_BASE   33088         // n-tile queue (single line)
#define TCNT_BASE   33089         // whqt-transpose completion counter
#define FLAG_WORDS  ((TCNT_BASE + 1) * FLAG_STRIDE)
#define NTILE       125           // 32000 / 256 proj n-tiles

__device__ __forceinline__ u16 f2bf(float f) {
    union { float f; unsigned u; } x; x.f = f;
    unsigned r = x.u + 0x7fff + ((x.u >> 16) & 1);   // RNE
    return (u16)(r >> 16);
}

// async global->LDS, 16B/lane. LDS dest wave-uniform base; HW adds lane*16. Global src per-lane.
__device__ __forceinline__ void gload_lds16(const u16* g, u16* l) {
    __builtin_amdgcn_global_load_lds(
        (const __attribute__((address_space(1))) void*)g,
        (__attribute__((address_space(3))) void*)l, 16, 0, 0);
}

// ================= prep: embedding gather ONLY ============
__global__ __launch_bounds__(256) void prep(
    const int* __restrict__ sent, const float* __restrict__ emb, u16* __restrict__ xb) {
    const int bx = blockIdx.x, tid = threadIdx.x;
    int row = bx * 2 + (tid >> 7);     // t*16+b
    int t = row >> 4, b = row & 15;
    int idx = sent[b * 128 + t];
    float4 v = ((const float4*)(emb + (size_t)idx * 512))[tid & 127];
    ushort4 s = { f2bf(v.x), f2bf(v.y), f2bf(v.z), f2bf(v.w) };
    ((ushort4*)(xb + (size_t)row * 512))[tid & 127] = s;
}

// ================= fused: LSTM (blocks 0..63) + proj workers (64..255), 512thr, 1 block/CU =====
// lstm (THIS ROUND — per-writer-wave flags):
//   writer wave w publishes its OWN flag (t,j,w) right after its own vmcnt drain (no LDS
//   atomicAdd aggregation, no last-wave indirection). Reader wave k: lane l polls flag line
//   (t-1)*256 + k*64 + l (16 sources x 4 parts = 64 lanes, one each); stages only after the
//   full ballot -> same 512B-group line-race safety as before.
//   Role split (r18): waves 4-7 poll+stage h & x; waves 0-3 compute zx_next while readers poll,
//   then 32 h-MFMAs from acc=zx_cur between B2 and B3.
// proj: champion (whqt transpose prologue, ONE n-tile per worker, m-sweep 0..15).
__global__ __launch_bounds__(512, 2) void lstm_proj(
    u16* __restrict__ hs,          // [128*16][1024] bf16, row = t*16+b
    const u16* __restrict__ xb,    // [128*16][512] bf16 embedded input
    const float* __restrict__ Wi, const float* __restrict__ Wf,
    const float* __restrict__ Wo, const float* __restrict__ Wc,
    const float* __restrict__ bi, const float* __restrict__ bf_,
    const float* __restrict__ bo, const float* __restrict__ bc,
    u32* __restrict__ flags,
    const float* __restrict__ Whq, // [1024][32000] f32 (source)
    u16* __restrict__ whqt,        // [32000][1024] bf16 (transposed here)
    const float* __restrict__ bq, float* __restrict__ out) {
    __shared__ __align__(16) char smem[135680];   // >81920 -> exactly 1 block/CU
    const int bx = blockIdx.x;
    const int tid = threadIdx.x;
    const int w = tid >> 6, l = tid & 63;

    // one-time cache invalidate (cross-replay staleness in L1/L2)
    if (tid == 0)
        __hip_atomic_fetch_add(&flags[(size_t)(ACQ_BASE + (bx & 255)) * FLAG_STRIDE], 0u,
                               __ATOMIC_ACQ_REL, __HIP_MEMORY_SCOPE_AGENT);

    if (bx < 64) {
        // ---------------- LSTM path ----------------
        u16* hstage = (u16*)smem;                              // 32 KB: [jw=64][b=16][2x16B]
        u16* xstage = (u16*)(smem + 32768);                    // 2 x 16 KB: [jx=32][b=16][2x16B]
        u16* wfx    = (u16*)(smem + 65536);                    // 64 KB: [gate][kk=16][lane][8]
        float (*zlds)[16][17] = (float (*)[16][17])(void*)(smem + 131072);  // 4352 B
        const int j = bx;
        const int row = l & 15, hi = l >> 4;

        // W_h B-frags in registers (rows 512..1535) + Wx B-frags in LDS (rows 0..511)
        bf16x8 wf[32];
        if (w < 4) {
            const float* Wg = (w == 0) ? Wi : (w == 1) ? Wf : (w == 2) ? Wo : Wc;
#pragma unroll
            for (int kk = 0; kk < 32; ++kk)
#pragma unroll
                for (int e = 0; e < 8; ++e)
                    wf[kk][e] = f2bf(Wg[(size_t)(512 + kk * 32 + hi * 8 + e) * 1024 + j * 16 + row]);
#pragma unroll
            for (int kk = 0; kk < 16; ++kk) {
                bf16x8 v;
#pragma unroll
                for (int e = 0; e < 8; ++e)
                    v[e] = f2bf(Wg[(size_t)(kk * 32 + hi * 8 + e) * 1024 + j * 16 + row]);
                *(bf16x8*)(wfx + ((size_t)(w * 16 + kk) * 64 + l) * 8) = v;
            }
        } else {
            // readers: stage x0 -> xbuf[0], x1 -> xbuf[1]
#pragma unroll
            for (int q = 0; q < 4; ++q) {
                int jx0 = ((w - 4) * 4 + q) * 2;
                gload_lds16(xb + (size_t)((l & 31) >> 1) * 512 + (jx0 + (l >> 5)) * 16 + (l & 1) * 8,
                            xstage + (size_t)jx0 * 256);
            }
#pragma unroll
            for (int q = 0; q < 4; ++q) {
                int jx0 = ((w - 4) * 4 + q) * 2;
                gload_lds16(xb + (size_t)(16 * 512 + ((l & 31) >> 1) * 512) + (jx0 + (l >> 5)) * 16 + (l & 1) * 8,
                            xstage + (size_t)(8192 + jx0 * 256));
            }
        }
        // per-thread gate biases
        float bzi = 0.f, bzf = 0.f, bzo = 0.f, bzc = 0.f;
        const int b = tid >> 4, hc = tid & 15;
        if (tid < 256) {
            bzi = bi[j * 16 + hc]; bzf = bf_[j * 16 + hc];
            bzo = bo[j * 16 + hc]; bzc = bc[j * 16 + hc];
        }
        __syncthreads();   // x0,x1 drained; wfx visible

        // zx_cur for t=0 (from xbuf[0])
        f32x4 zz4 = { 0.f, 0.f, 0.f, 0.f };
        f32x4 zxc0 = zz4, zxc1 = zz4, zxc2 = zz4, zxc3 = zz4;
        if (w < 4) {
#pragma unroll
            for (int kk = 0; kk < 16; kk += 4) {
#pragma unroll
                for (int u = 0; u < 4; ++u) {
                    int c = kk + u;
                    bf16x8 a = *(const bf16x8*)(xstage + (2 * c + (hi >> 1)) * 256
                                                + row * 16 + (hi & 1) * 8);
                    bf16x8 bxv = *(const bf16x8*)(wfx + ((size_t)(w * 16 + c) * 64 + l) * 8);
                    f32x4& ac = (u == 0) ? zxc0 : (u == 1) ? zxc1 : (u == 2) ? zxc2 : zxc3;
                    ac = __builtin_amdgcn_mfma_f32_16x16x32_bf16(a, bxv, ac, 0, 0, 0);
                }
            }
        }
        float cst = 0.f;

        for (int t = 0; t < 128; ++t) {
            f32x4 zxn0 = zz4, zxn1 = zz4, zxn2 = zz4, zxn3 = zz4;
            if (w >= 4) {
                // ---- readers: issue x_{t+2} stage into xbuf[t&1]
                if (t < 126) {
                    const u16* xbase = xb + (size_t)(t + 2) * 16 * 512;
                    u16* xd = xstage + (t & 1) * 8192;
#pragma unroll
                    for (int q = 0; q < 4; ++q) {
                        int jx0 = ((w - 4) * 4 + q) * 2;
                        gload_lds16(xbase + (size_t)((l & 31) >> 1) * 512 + (jx0 + (l >> 5)) * 16 + (l & 1) * 8,
                                    xd + (size_t)jx0 * 256);
                    }
                }
                if (t > 0) {
                    // ---- poll: lane l watches flag line (t-1)*256 + (w-4)*64 + l
                    //      (16 sources x 4 writer-wave parts; full ballot before staging)
                    {
                        const size_t base = (size_t)(t - 1) * 256 + (size_t)(w - 4) * 64 + l;
                        int spins = 0;
                        while (true) {
                            u32 f = __hip_atomic_load(&flags[base * FLAG_STRIDE],
                                                      __ATOMIC_RELAXED, __HIP_MEMORY_SCOPE_SYSTEM);
                            if (__ballot(f != 0u) == ~0ull) break;
                            __builtin_amdgcn_s_sleep(1);
                            if (++spins > (1 << 20)) break;   // safety bail
                        }
                    }
                    // ---- stage the 16 slices: 8 full-wave 1KB loads (2 slices each)
                    const u16* hbase = hs + (size_t)(t - 1) * 16 * 1024;
#pragma unroll
                    for (int q = 0; q < 8; ++q) {
                        int jw0 = (w - 4) * 16 + 2 * q;
                        gload_lds16(hbase + (size_t)((l & 31) >> 1) * 1024
                                          + (jw0 + (l >> 5)) * 16 + (l & 1) * 8,
                                    hstage + (size_t)jw0 * 256);
                    }
                }
            } else {
                // ---- writers: compute zx_next = x_{t+1} @ Wx (operands drained >=1 step ago)
                if (t < 127) {
                    const u16* xs = xstage + ((t + 1) & 1) * 8192;
#pragma unroll
                    for (int kk = 0; kk < 16; kk += 4) {
#pragma unroll
                        for (int u = 0; u < 4; ++u) {
                            int c = kk + u;
                            bf16x8 a = *(const bf16x8*)(xs + (2 * c + (hi >> 1)) * 256
                                                        + row * 16 + (hi & 1) * 8);
                            bf16x8 bxv = *(const bf16x8*)(wfx + ((size_t)(w * 16 + c) * 64 + l) * 8);
                            f32x4& ac = (u == 0) ? zxn0 : (u == 1) ? zxn1 : (u == 2) ? zxn2 : zxn3;
                            ac = __builtin_amdgcn_mfma_f32_16x16x32_bf16(a, bxv, ac, 0, 0, 0);
                        }
                    }
                }
            }
            __syncthreads();   // B2: h slices (+x stage) drained -> LDS consistent
            if (t > 0 && tid == 0)   // all flags of t-1 confirmed block-wide -> epoch
                __hip_atomic_store(&flags[(size_t)(EPOCH_BASE + j) * FLAG_STRIDE], (u32)t,
                                   __ATOMIC_RELAXED, __HIP_MEMORY_SCOPE_SYSTEM);
            if (w < 4) {
                f32x4 ac0 = zxc0, ac1 = zxc1, ac2 = zxc2, ac3 = zxc3;
                if (t > 0) {
#pragma unroll
                    for (int kk = 0; kk < 32; kk += 4) {
#pragma unroll
                        for (int u = 0; u < 4; ++u) {
                            int c = kk + u;
                            int base = (2 * c + (hi >> 1)) * 256 + row * 16 + (hi & 1) * 8;
                            bf16x8 a = *(const bf16x8*)(hstage + base);
                            f32x4& ac = (u == 0) ? ac0 : (u == 1) ? ac1 : (u == 2) ? ac2 : ac3;
                            ac = __builtin_amdgcn_mfma_f32_16x16x32_bf16(a, wf[c], ac, 0, 0, 0);
                        }
                    }
                }
                f32x4 acc = (ac0 + ac1) + (ac2 + ac3);
#pragma unroll
                for (int r = 0; r < 4; ++r)
                    zlds[w][hi * 4 + r][row] = acc[r];
            }
            __syncthreads();       // B3: zlds ready; guards hstage/xstage reuse
            if (tid < 256) {
                float zi = zlds[0][b][hc] + bzi;
                float zf = zlds[1][b][hc] + bzf;
                float zo = zlds[2][b][hc] + bzo;
                float zc = zlds[3][b][hc] + bzc;
                float ig = 1.f / (1.f + __expf(-zi));
                float fg = 1.f / (1.f + __expf(-zf));
                float og = 1.f / (1.f + __expf(-zo));
                float gg = tanhf(zc);
                cst = fg * cst + ig * gg;
                float h = og * tanhf(cst);
                float hn = __shfl_xor(h, 1);
                if (!(l & 1)) {
                    unsigned pk = (unsigned)f2bf(h) | ((unsigned)f2bf(hn) << 16);
                    u32* dst = (u32*)hs + (((size_t)(t * 16 + b) * 1024 + j * 16 + hc) >> 1);
                    __hip_atomic_store(dst, pk, __ATOMIC_RELAXED, __HIP_MEMORY_SCOPE_SYSTEM);
                }
            }
            if (w < 4) {
                // per-wave drain + OWN flag publish (no cross-wave aggregation)
                asm volatile("s_waitcnt vmcnt(0)" ::: "memory");
                if (l == 0)
                    __hip_atomic_store(&flags[((size_t)t * 256 + (size_t)j * 4 + w) * FLAG_STRIDE],
                                       1u, __ATOMIC_RELAXED, __HIP_MEMORY_SCOPE_SYSTEM);
                zxc0 = zxn0; zxc1 = zxn1; zxc2 = zxn2; zxc3 = zxn3;
            }
        }
        // final: readers confirm step-127 flags globally, then epoch = 128
        if (w >= 4) {
            const size_t base = (size_t)127 * 256 + (size_t)(w - 4) * 64 + l;
            int spins = 0;
            while (true) {
                u32 f = __hip_atomic_load(&flags[base * FLAG_STRIDE],
                                          __ATOMIC_RELAXED, __HIP_MEMORY_SCOPE_SYSTEM);
                if (__ballot(f != 0u) == ~0ull) break;
                __builtin_amdgcn_s_sleep(1);
                if (++spins > (1 << 20)) break;
            }
        }
        __syncthreads();
        if (tid == 0)
            __hip_atomic_store(&flags[(size_t)(EPOCH_BASE + j) * FLAG_STRIDE], 128u,
                               __ATOMIC_RELAXED, __HIP_MEMORY_SCOPE_SYSTEM);
        return;
    }

    // ---------------- projection worker ----------------
    // Prologue: cooperative whqt transpose (hidden by n-outer slack). System-scope stores;
    // TCNT counter gates whqt reads.
    {
        float (*tp)[32][33] = (float (*)[32][33])(void*)smem;   // 8448 B
        const int half = tid >> 8, t256 = tid & 255;
        const int r = t256 >> 3, cq = (t256 & 7) * 4;
        const int c = t256 >> 3, rq = (t256 & 7) * 4;
        for (int it = 0; it < 84; ++it) {
            int q = it * 384 + (bx - 64) * 2 + half;
            bool act = q < 32000;
            int rt = 0, ct = 0;
            if (act) { rt = (q / 1000) * 32; ct = (q % 1000) * 32; }
            if (act) {
                float4 v = *(const float4*)(Whq + (size_t)(rt + r) * 32000 + ct + cq);
                tp[half][r][cq] = v.x; tp[half][r][cq + 1] = v.y;
                tp[half][r][cq + 2] = v.z; tp[half][r][cq + 3] = v.w;
            }
            __syncthreads();
            if (act) {
                u64 pk = (u64)f2bf(tp[half][rq][c])
                       | ((u64)f2bf(tp[half][rq + 1][c]) << 16)
                       | ((u64)f2bf(tp[half][rq + 2][c]) << 32)
                       | ((u64)f2bf(tp[half][rq + 3][c]) << 48);
                __hip_atomic_store((u64*)(whqt + (size_t)(ct + c) * 1024 + rt + rq), pk,
                                   __ATOMIC_RELAXED, __HIP_MEMORY_SCOPE_SYSTEM);
            }
            __syncthreads();
        }
        asm volatile("s_waitcnt vmcnt(0)" ::: "memory");
        if (tid == 0)
            __hip_atomic_fetch_add(&flags[(size_t)TCNT_BASE * FLAG_STRIDE], 1u,
                                   __ATOMIC_RELAXED, __HIP_MEMORY_SCOPE_SYSTEM);
    }

    u16* As = (u16*)smem;                   // 2 x 16 KB
    u16* Bs = (u16*)(smem + 32768);         // 2 x 32 KB
    u32* idx_slot = (u32*)(smem + 98304);
    const int wr = w >> 2, wc = w & 3;
    const int lr = l >> 4, lc = l & 15;

    // grab ONE n-tile for the whole run; wait for transpose completion (all 192 blocks)
    if (tid == 0)
        *idx_slot = __hip_atomic_fetch_add(&flags[(size_t)QCNT_BASE * FLAG_STRIDE],
                                           1u, __ATOMIC_RELAXED, __HIP_MEMORY_SCOPE_AGENT);
    if (w == 0) {
        int spins = 0;
        while (__hip_atomic_load(&flags[(size_t)TCNT_BASE * FLAG_STRIDE],
                                 __ATOMIC_RELAXED, __HIP_MEMORY_SCOPE_SYSTEM) < 192u) {
            __builtin_amdgcn_s_sleep(8);
            if (++spins > (1 << 20)) break;
        }
    }
    __syncthreads();
    const u32 myIdx = *idx_slot;
    if (myIdx >= NTILE) return;             // 67 surplus workers exit
    const int n0 = (int)myIdx * 256;

    for (int m = 0; m < 16; ++m) {
        if (w == 0) {                       // wait for t-chunk m readiness (one epoch line)
            const u32 need = (u32)(8 * m + 8);
            int spins = 0;
            while (__hip_atomic_load(&flags[(size_t)(EPOCH_BASE + (bx & 63)) * FLAG_STRIDE],
                                     __ATOMIC_RELAXED, __HIP_MEMORY_SCOPE_SYSTEM) < need) {
                __builtin_amdgcn_s_sleep(8);
                if (++spins > (1 << 20)) break;
            }
        }
        __syncthreads();

        auto STAGE = [&](int bi, int kt) {
#pragma unroll
            for (int i = 0; i < 2; ++i) {           // A: 128 rows x 8 chunks
                int C = i * 512 + tid, r = C >> 3, c = C & 7;
                int sc = c ^ (r & 7);
                int arow = (8 * m + (r & 7)) * 16 + (r >> 3);   // b-major within chunk
                gload_lds16(hs + (size_t)arow * 1024 + kt * 64 + sc * 8,
                            As + (size_t)(bi * 8192 + (i * 512 + w * 64) * 8));
            }
#pragma unroll
            for (int i = 0; i < 4; ++i) {           // B: 256 rows x 8 chunks
                int C = i * 512 + tid, r = C >> 3, c = C & 7;
                int sc = c ^ (r & 7);
                gload_lds16(whqt + (size_t)(n0 + r) * 1024 + kt * 64 + sc * 8,
                            Bs + (size_t)(bi * 16384 + (i * 512 + w * 64) * 8));
            }
        };

        f32x4 acc[4][4];
        f32x4 zz = { 0.f, 0.f, 0.f, 0.f };
#pragma unroll
        for (int i = 0; i < 4; i++)
#pragma unroll
            for (int jj = 0; jj < 4; jj++) acc[i][jj] = zz;

        int cur = 0;
        STAGE(0, 0);
        __syncthreads();
        for (int kt = 0; kt < 16; ++kt) {
            if (kt + 1 < 16) STAGE(cur ^ 1, kt + 1);
            const u16* Ab = As + cur * 8192;
            const u16* Bb = Bs + cur * 16384;
#pragma unroll
            for (int kk = 0; kk < 2; ++kk) {
                bf16x8 af[4], bf[4];
#pragma unroll
                for (int mi = 0; mi < 4; ++mi) {
                    int rA = wr * 64 + mi * 16 + lc;
                    int s = (kk * 4 + lr) ^ (rA & 7);
                    af[mi] = *(const bf16x8*)(Ab + rA * 64 + s * 8);
                }
#pragma unroll
                for (int ni = 0; ni < 4; ++ni) {
                    int rB = wc * 64 + ni * 16 + lc;
                    int s = (kk * 4 + lr) ^ (rB & 7);
                    bf[ni] = *(const bf16x8*)(Bb + rB * 64 + s * 8);
                }
#pragma unroll
                for (int mi = 0; mi < 4; ++mi)
#pragma unroll
                    for (int ni = 0; ni < 4; ++ni)
                        acc[mi][ni] = __builtin_amdgcn_mfma_f32_16x16x32_bf16(af[mi], bf[ni], acc[mi][ni], 0, 0, 0);
            }
            __syncthreads();   // drains vmcnt (next stage landed) + guards buf reuse
            cur ^= 1;
        }
#pragma unroll
        for (int ni = 0; ni < 4; ni++) {
            int col = n0 + wc * 64 + ni * 16 + lc;
            float bv = bq[col];
#pragma unroll
            for (int mi = 0; mi < 4; mi++) {
                int r0 = wr * 64 + mi * 16 + lr * 4;
                int bb = r0 >> 3;
                int t0 = 8 * m + (r0 & 7);
                float4 st = { acc[mi][ni][0] + bv, acc[mi][ni][1] + bv,
                              acc[mi][ni][2] + bv, acc[mi][ni][3] + bv };
                *(float4*)(out + (size_t)bb * 4096000 + (size_t)col * 128 + t0) = st;
            }
        }
    }
}

extern "C" void kernel_launch(void* const* d_in, const int* in_sizes, int n_in,
                              void* d_out, int out_size, void* d_ws, size_t ws_size,
                              hipStream_t stream) {
    const int*   sent = (const int*)d_in[0];
    const float* emb  = (const float*)d_in[1];
    const float* W_i  = (const float*)d_in[2];
    const float* b_i  = (const float*)d_in[3];
    const float* W_f  = (const float*)d_in[4];
    const float* b_f  = (const float*)d_in[5];
    const float* W_o  = (const float*)d_in[6];
    const float* b_o  = (const float*)d_in[7];
    const float* W_c  = (const float*)d_in[8];
    const float* b_c  = (const float*)d_in[9];
    const float* W_hq = (const float*)d_in[10];
    const float* b_q  = (const float*)d_in[11];
    float* out = (float*)d_out;

    char* ws = (char*)d_ws;
    size_t off = 0;
    auto alloc = [&](size_t bytes) { void* p = ws + off; off += (bytes + 255) & ~255ull; return p; };
    u32*   flags = (u32*)alloc((size_t)FLAG_WORDS * 4);
    u16*   xb   = (u16*)alloc((size_t)2048 * 512 * 2);
    u16*   hs   = (u16*)alloc((size_t)2048 * 1024 * 2);
    u16*   whqt = (u16*)alloc((size_t)32000 * 1024 * 2);

    hipMemsetAsync(flags, 0, (size_t)FLAG_WORDS * 4, stream);
    // prep: embedding gather only
    prep<<<1024, 256, 0, stream>>>(sent, emb, xb);
    // fused: 64 lstm blocks (role-split waves, per-wave flags) + 192 proj workers
    lstm_proj<<<256, 512, 0, stream>>>(hs, xb, W_i, W_f, W_o, W_c,
                                       b_i, b_f, b_o, b_c,
                                       flags, W_hq, whqt, b_q, out);
}

// Round 20
// 625.513 us; speedup vs baseline: 1.1157x; 1.1157x over previous
//
#include <hip/hip_runtime.h>
#include <math.h>

typedef float f32x4 __attribute__((ext_vector_type(4)));
typedef short bf16x8 __attribute__((ext_vector_type(8)));
typedef unsigned short u16;
typedef unsigned int u32;
typedef unsigned long long u64;

#define FLAG_STRIDE 16            // one u32 flag per 64B line
#define ACQ_BASE    8192          // 256 acquire-dummy lines (after 128*64 step flags)
#define EPOCH_BASE  8448          // 64 epoch lines
#define QCNT_BASE   8512          // n-tile queue (single line)
#define TCNT_BASE   8528          // whqt-transpose completion counter
#define FLAG_WORDS  ((TCNT_BASE + 1) * FLAG_STRIDE)
#define NTILE       125           // 32000 / 256 proj n-tiles

__device__ __forceinline__ u16 f2bf(float f) {
    union { float f; unsigned u; } x; x.f = f;
    unsigned r = x.u + 0x7fff + ((x.u >> 16) & 1);   // RNE
    return (u16)(r >> 16);
}

// async global->LDS, 16B/lane. LDS dest wave-uniform base; HW adds lane*16. Global src per-lane.
__device__ __forceinline__ void gload_lds16(const u16* g, u16* l) {
    __builtin_amdgcn_global_load_lds(
        (const __attribute__((address_space(1))) void*)g,
        (__attribute__((address_space(3))) void*)l, 16, 0, 0);
}

// ================= prep: embedding gather ONLY ============
__global__ __launch_bounds__(256) void prep(
    const int* __restrict__ sent, const float* __restrict__ emb, u16* __restrict__ xb) {
    const int bx = blockIdx.x, tid = threadIdx.x;
    int row = bx * 2 + (tid >> 7);     // t*16+b
    int t = row >> 4, b = row & 15;
    int idx = sent[b * 128 + t];
    float4 v = ((const float4*)(emb + (size_t)idx * 512))[tid & 127];
    ushort4 s = { f2bf(v.x), f2bf(v.y), f2bf(v.z), f2bf(v.w) };
    ((ushort4*)(xb + (size_t)row * 512))[tid & 127] = s;
}

// ================= fused: LSTM (blocks 0..63) + proj workers (64..255), 512thr, 1 block/CU =====
// lstm (r18 champion — wave role split):
//   waves 4-7 (readers): own ALL flag polling (wave 4+k: 16 flags via lanes 0-15, 512B-aligned
//     group -> line-race-safe) + ALL h staging (8 full-wave 1KB loads each) + x staging (2 steps
//     ahead, double-buffered). Their poll starts right after B3 -> detection overlaps writers'
//     store chain.
//   waves 0-3 (writers): gates/store/publish (lds_cnt aggregation, last wave publishes), then
//     compute zx_next = x_{t+1}@Wx (16 MFMAs, operands drained >=1 step ago) WHILE readers poll
//     -> B2->B3 shrinks to 32 h-MFMAs starting from acc = zx_cur.
// proj: whqt transpose prologue (hidden by n-outer slack), ONE n-tile per worker, m-sweep 0..15.
__global__ __launch_bounds__(512, 2) void lstm_proj(
    u16* __restrict__ hs,          // [128*16][1024] bf16, row = t*16+b
    const u16* __restrict__ xb,    // [128*16][512] bf16 embedded input
    const float* __restrict__ Wi, const float* __restrict__ Wf,
    const float* __restrict__ Wo, const float* __restrict__ Wc,
    const float* __restrict__ bi, const float* __restrict__ bf_,
    const float* __restrict__ bo, const float* __restrict__ bc,
    u32* __restrict__ flags,
    const float* __restrict__ Whq, // [1024][32000] f32 (source)
    u16* __restrict__ whqt,        // [32000][1024] bf16 (transposed here)
    const float* __restrict__ bq, float* __restrict__ out) {
    __shared__ __align__(16) char smem[135680];   // >81920 -> exactly 1 block/CU
    const int bx = blockIdx.x;
    const int tid = threadIdx.x;
    const int w = tid >> 6, l = tid & 63;

    // one-time cache invalidate (cross-replay staleness in L1/L2)
    if (tid == 0)
        __hip_atomic_fetch_add(&flags[(size_t)(ACQ_BASE + (bx & 255)) * FLAG_STRIDE], 0u,
                               __ATOMIC_ACQ_REL, __HIP_MEMORY_SCOPE_AGENT);

    if (bx < 64) {
        // ---------------- LSTM path ----------------
        u16* hstage = (u16*)smem;                              // 32 KB: [jw=64][b=16][2x16B]
        u16* xstage = (u16*)(smem + 32768);                    // 2 x 16 KB: [jx=32][b=16][2x16B]
        u16* wfx    = (u16*)(smem + 65536);                    // 64 KB: [gate][kk=16][lane][8]
        float (*zlds)[16][17] = (float (*)[16][17])(void*)(smem + 131072);  // 4352 B
        u32* lds_cnt = (u32*)(smem + 135424);
        const int j = bx;
        const int row = l & 15, hi = l >> 4;
        if (tid == 0) *lds_cnt = 0;

        // W_h B-frags in registers (rows 512..1535) + Wx B-frags in LDS (rows 0..511)
        bf16x8 wf[32];
        if (w < 4) {
            const float* Wg = (w == 0) ? Wi : (w == 1) ? Wf : (w == 2) ? Wo : Wc;
#pragma unroll
            for (int kk = 0; kk < 32; ++kk)
#pragma unroll
                for (int e = 0; e < 8; ++e)
                    wf[kk][e] = f2bf(Wg[(size_t)(512 + kk * 32 + hi * 8 + e) * 1024 + j * 16 + row]);
#pragma unroll
            for (int kk = 0; kk < 16; ++kk) {
                bf16x8 v;
#pragma unroll
                for (int e = 0; e < 8; ++e)
                    v[e] = f2bf(Wg[(size_t)(kk * 32 + hi * 8 + e) * 1024 + j * 16 + row]);
                *(bf16x8*)(wfx + ((size_t)(w * 16 + kk) * 64 + l) * 8) = v;
            }
        } else {
            // readers: stage x0 -> xbuf[0], x1 -> xbuf[1]
#pragma unroll
            for (int q = 0; q < 4; ++q) {
                int jx0 = ((w - 4) * 4 + q) * 2;
                gload_lds16(xb + (size_t)((l & 31) >> 1) * 512 + (jx0 + (l >> 5)) * 16 + (l & 1) * 8,
                            xstage + (size_t)jx0 * 256);
            }
#pragma unroll
            for (int q = 0; q < 4; ++q) {
                int jx0 = ((w - 4) * 4 + q) * 2;
                gload_lds16(xb + (size_t)(16 * 512 + ((l & 31) >> 1) * 512) + (jx0 + (l >> 5)) * 16 + (l & 1) * 8,
                            xstage + (size_t)(8192 + jx0 * 256));
            }
        }
        // per-thread gate biases
        float bzi = 0.f, bzf = 0.f, bzo = 0.f, bzc = 0.f;
        const int b = tid >> 4, hc = tid & 15;
        if (tid < 256) {
            bzi = bi[j * 16 + hc]; bzf = bf_[j * 16 + hc];
            bzo = bo[j * 16 + hc]; bzc = bc[j * 16 + hc];
        }
        __syncthreads();   // x0,x1 drained; wfx visible

        // zx_cur for t=0 (from xbuf[0])
        f32x4 zz4 = { 0.f, 0.f, 0.f, 0.f };
        f32x4 zxc0 = zz4, zxc1 = zz4, zxc2 = zz4, zxc3 = zz4;
        if (w < 4) {
#pragma unroll
            for (int kk = 0; kk < 16; kk += 4) {
#pragma unroll
                for (int u = 0; u < 4; ++u) {
                    int c = kk + u;
                    bf16x8 a = *(const bf16x8*)(xstage + (2 * c + (hi >> 1)) * 256
                                                + row * 16 + (hi & 1) * 8);
                    bf16x8 bxv = *(const bf16x8*)(wfx + ((size_t)(w * 16 + c) * 64 + l) * 8);
                    f32x4& ac = (u == 0) ? zxc0 : (u == 1) ? zxc1 : (u == 2) ? zxc2 : zxc3;
                    ac = __builtin_amdgcn_mfma_f32_16x16x32_bf16(a, bxv, ac, 0, 0, 0);
                }
            }
        }
        float cst = 0.f;

        for (int t = 0; t < 128; ++t) {
            f32x4 zxn0 = zz4, zxn1 = zz4, zxn2 = zz4, zxn3 = zz4;
            if (w >= 4) {
                // ---- readers: issue x_{t+2} stage into xbuf[t&1]
                if (t < 126) {
                    const u16* xbase = xb + (size_t)(t + 2) * 16 * 512;
                    u16* xd = xstage + (t & 1) * 8192;
#pragma unroll
                    for (int q = 0; q < 4; ++q) {
                        int jx0 = ((w - 4) * 4 + q) * 2;
                        gload_lds16(xbase + (size_t)((l & 31) >> 1) * 512 + (jx0 + (l >> 5)) * 16 + (l & 1) * 8,
                                    xd + (size_t)jx0 * 256);
                    }
                }
                if (t > 0) {
                    // ---- poll this wave's 16 source flags (lanes 0-15), 512B-aligned group
                    {
                        int spins = 0;
                        while (true) {
                            u32 f = 1u;
                            if (l < 16)
                                f = __hip_atomic_load(
                                        &flags[(size_t)((t - 1) * 64 + (w - 4) * 16 + l) * FLAG_STRIDE],
                                        __ATOMIC_RELAXED, __HIP_MEMORY_SCOPE_SYSTEM);
                            if (__ballot(f != 0u) == ~0ull) break;
                            __builtin_amdgcn_s_sleep(1);
                            if (++spins > (1 << 20)) break;   // safety bail
                        }
                    }
                    // ---- stage the 16 slices: 8 full-wave 1KB loads (2 slices each)
                    const u16* hbase = hs + (size_t)(t - 1) * 16 * 1024;
#pragma unroll
                    for (int q = 0; q < 8; ++q) {
                        int jw0 = (w - 4) * 16 + 2 * q;
                        gload_lds16(hbase + (size_t)((l & 31) >> 1) * 1024
                                          + (jw0 + (l >> 5)) * 16 + (l & 1) * 8,
                                    hstage + (size_t)jw0 * 256);
                    }
                }
            } else {
                // ---- writers: compute zx_next = x_{t+1} @ Wx (operands drained >=1 step ago)
                if (t < 127) {
                    const u16* xs = xstage + ((t + 1) & 1) * 8192;
#pragma unroll
                    for (int kk = 0; kk < 16; kk += 4) {
#pragma unroll
                        for (int u = 0; u < 4; ++u) {
                            int c = kk + u;
                            bf16x8 a = *(const bf16x8*)(xs + (2 * c + (hi >> 1)) * 256
                                                        + row * 16 + (hi & 1) * 8);
                            bf16x8 bxv = *(const bf16x8*)(wfx + ((size_t)(w * 16 + c) * 64 + l) * 8);
                            f32x4& ac = (u == 0) ? zxn0 : (u == 1) ? zxn1 : (u == 2) ? zxn2 : zxn3;
                            ac = __builtin_amdgcn_mfma_f32_16x16x32_bf16(a, bxv, ac, 0, 0, 0);
                        }
                    }
                }
            }
            __syncthreads();   // B2: h slices (+x stage) drained -> LDS consistent
            if (t > 0 && tid == 0)   // all flags of t-1 confirmed block-wide -> epoch
                __hip_atomic_store(&flags[(size_t)(EPOCH_BASE + j) * FLAG_STRIDE], (u32)t,
                                   __ATOMIC_RELAXED, __HIP_MEMORY_SCOPE_SYSTEM);
            if (w < 4) {
                f32x4 ac0 = zxc0, ac1 = zxc1, ac2 = zxc2, ac3 = zxc3;
                if (t > 0) {
#pragma unroll
                    for (int kk = 0; kk < 32; kk += 4) {
#pragma unroll
                        for (int u = 0; u < 4; ++u) {
                            int c = kk + u;
                            int base = (2 * c + (hi >> 1)) * 256 + row * 16 + (hi & 1) * 8;
                            bf16x8 a = *(const bf16x8*)(hstage + base);
                            f32x4& ac = (u == 0) ? ac0 : (u == 1) ? ac1 : (u == 2) ? ac2 : ac3;
                            ac = __builtin_amdgcn_mfma_f32_16x16x32_bf16(a, wf[c], ac, 0, 0, 0);
                        }
                    }
                }
                f32x4 acc = (ac0 + ac1) + (ac2 + ac3);
#pragma unroll
                for (int r = 0; r < 4; ++r)
                    zlds[w][hi * 4 + r][row] = acc[r];
            }
            __syncthreads();       // B3: zlds ready; guards hstage/xstage reuse
            if (tid < 256) {
                float zi = zlds[0][b][hc] + bzi;
                float zf = zlds[1][b][hc] + bzf;
                float zo = zlds[2][b][hc] + bzo;
                float zc = zlds[3][b][hc] + bzc;
                float ig = 1.f / (1.f + __expf(-zi));
                float fg = 1.f / (1.f + __expf(-zf));
                float og = 1.f / (1.f + __expf(-zo));
                float gg = tanhf(zc);
                cst = fg * cst + ig * gg;
                float h = og * tanhf(cst);
                float hn = __shfl_xor(h, 1);
                if (!(l & 1)) {
                    unsigned pk = (unsigned)f2bf(h) | ((unsigned)f2bf(hn) << 16);
                    u32* dst = (u32*)hs + (((size_t)(t * 16 + b) * 1024 + j * 16 + hc) >> 1);
                    __hip_atomic_store(dst, pk, __ATOMIC_RELAXED, __HIP_MEMORY_SCOPE_SYSTEM);
                }
            }
            if (w < 4) {
                asm volatile("s_waitcnt vmcnt(0)" ::: "memory");
                if (l == 0) {
                    u32 old = atomicAdd(lds_cnt, 1u);
                    if (old == (u32)(4 * t + 3))
                        __hip_atomic_store(&flags[(size_t)(t * 64 + j) * FLAG_STRIDE], 1u,
                                           __ATOMIC_RELAXED, __HIP_MEMORY_SCOPE_SYSTEM);
                }
                zxc0 = zxn0; zxc1 = zxn1; zxc2 = zxn2; zxc3 = zxn3;
            }
        }
        // final: confirm step 127 globally, then epoch = 128
        if (w == 0) {
            int spins = 0;
            while (true) {
                u32 f = __hip_atomic_load(&flags[(size_t)(127 * 64 + l) * FLAG_STRIDE],
                                          __ATOMIC_RELAXED, __HIP_MEMORY_SCOPE_SYSTEM);
                if (__ballot(f != 0) == ~0ull) break;
                __builtin_amdgcn_s_sleep(1);
                if (++spins > (1 << 20)) break;
            }
            if (l == 0)
                __hip_atomic_store(&flags[(size_t)(EPOCH_BASE + j) * FLAG_STRIDE], 128u,
                                   __ATOMIC_RELAXED, __HIP_MEMORY_SCOPE_SYSTEM);
        }
        return;
    }

    // ---------------- projection worker ----------------
    // Prologue: cooperative whqt transpose (hidden by n-outer slack). System-scope stores;
    // TCNT counter gates whqt reads.
    {
        float (*tp)[32][33] = (float (*)[32][33])(void*)smem;   // 8448 B
        const int half = tid >> 8, t256 = tid & 255;
        const int r = t256 >> 3, cq = (t256 & 7) * 4;
        const int c = t256 >> 3, rq = (t256 & 7) * 4;
        for (int it = 0; it < 84; ++it) {
            int q = it * 384 + (bx - 64) * 2 + half;
            bool act = q < 32000;
            int rt = 0, ct = 0;
            if (act) { rt = (q / 1000) * 32; ct = (q % 1000) * 32; }
            if (act) {
                float4 v = *(const float4*)(Whq + (size_t)(rt + r) * 32000 + ct + cq);
                tp[half][r][cq] = v.x; tp[half][r][cq + 1] = v.y;
                tp[half][r][cq + 2] = v.z; tp[half][r][cq + 3] = v.w;
            }
            __syncthreads();
            if (act) {
                u64 pk = (u64)f2bf(tp[half][rq][c])
                       | ((u64)f2bf(tp[half][rq + 1][c]) << 16)
                       | ((u64)f2bf(tp[half][rq + 2][c]) << 32)
                       | ((u64)f2bf(tp[half][rq + 3][c]) << 48);
                __hip_atomic_store((u64*)(whqt + (size_t)(ct + c) * 1024 + rt + rq), pk,
                                   __ATOMIC_RELAXED, __HIP_MEMORY_SCOPE_SYSTEM);
            }
            __syncthreads();
        }
        asm volatile("s_waitcnt vmcnt(0)" ::: "memory");
        if (tid == 0)
            __hip_atomic_fetch_add(&flags[(size_t)TCNT_BASE * FLAG_STRIDE], 1u,
                                   __ATOMIC_RELAXED, __HIP_MEMORY_SCOPE_SYSTEM);
    }

    u16* As = (u16*)smem;                   // 2 x 16 KB
    u16* Bs = (u16*)(smem + 32768);         // 2 x 32 KB
    u32* idx_slot = (u32*)(smem + 98304);
    const int wr = w >> 2, wc = w & 3;
    const int lr = l >> 4, lc = l & 15;

    // grab ONE n-tile for the whole run; wait for transpose completion (all 192 blocks)
    if (tid == 0)
        *idx_slot = __hip_atomic_fetch_add(&flags[(size_t)QCNT_BASE * FLAG_STRIDE],
                                           1u, __ATOMIC_RELAXED, __HIP_MEMORY_SCOPE_AGENT);
    if (w == 0) {
        int spins = 0;
        while (__hip_atomic_load(&flags[(size_t)TCNT_BASE * FLAG_STRIDE],
                                 __ATOMIC_RELAXED, __HIP_MEMORY_SCOPE_SYSTEM) < 192u) {
            __builtin_amdgcn_s_sleep(8);
            if (++spins > (1 << 20)) break;
        }
    }
    __syncthreads();
    const u32 myIdx = *idx_slot;
    if (myIdx >= NTILE) return;             // 67 surplus workers exit
    const int n0 = (int)myIdx * 256;

    for (int m = 0; m < 16; ++m) {
        if (w == 0) {                       // wait for t-chunk m readiness (one epoch line)
            const u32 need = (u32)(8 * m + 8);
            int spins = 0;
            while (__hip_atomic_load(&flags[(size_t)(EPOCH_BASE + (bx & 63)) * FLAG_STRIDE],
                                     __ATOMIC_RELAXED, __HIP_MEMORY_SCOPE_SYSTEM) < need) {
                __builtin_amdgcn_s_sleep(8);
                if (++spins > (1 << 20)) break;
            }
        }
        __syncthreads();

        auto STAGE = [&](int bi, int kt) {
#pragma unroll
            for (int i = 0; i < 2; ++i) {           // A: 128 rows x 8 chunks
                int C = i * 512 + tid, r = C >> 3, c = C & 7;
                int sc = c ^ (r & 7);
                int arow = (8 * m + (r & 7)) * 16 + (r >> 3);   // b-major within chunk
                gload_lds16(hs + (size_t)arow * 1024 + kt * 64 + sc * 8,
                            As + (size_t)(bi * 8192 + (i * 512 + w * 64) * 8));
            }
#pragma unroll
            for (int i = 0; i < 4; ++i) {           // B: 256 rows x 8 chunks
                int C = i * 512 + tid, r = C >> 3, c = C & 7;
                int sc = c ^ (r & 7);
                gload_lds16(whqt + (size_t)(n0 + r) * 1024 + kt * 64 + sc * 8,
                            Bs + (size_t)(bi * 16384 + (i * 512 + w * 64) * 8));
            }
        };

        f32x4 acc[4][4];
        f32x4 zz = { 0.f, 0.f, 0.f, 0.f };
#pragma unroll
        for (int i = 0; i < 4; i++)
#pragma unroll
            for (int jj = 0; jj < 4; jj++) acc[i][jj] = zz;

        int cur = 0;
        STAGE(0, 0);
        __syncthreads();
        for (int kt = 0; kt < 16; ++kt) {
            if (kt + 1 < 16) STAGE(cur ^ 1, kt + 1);
            const u16* Ab = As + cur * 8192;
            const u16* Bb = Bs + cur * 16384;
#pragma unroll
            for (int kk = 0; kk < 2; ++kk) {
                bf16x8 af[4], bf[4];
#pragma unroll
                for (int mi = 0; mi < 4; ++mi) {
                    int rA = wr * 64 + mi * 16 + lc;
                    int s = (kk * 4 + lr) ^ (rA & 7);
                    af[mi] = *(const bf16x8*)(Ab + rA * 64 + s * 8);
                }
#pragma unroll
                for (int ni = 0; ni < 4; ++ni) {
                    int rB = wc * 64 + ni * 16 + lc;
                    int s = (kk * 4 + lr) ^ (rB & 7);
                    bf[ni] = *(const bf16x8*)(Bb + rB * 64 + s * 8);
                }
#pragma unroll
                for (int mi = 0; mi < 4; ++mi)
#pragma unroll
                    for (int ni = 0; ni < 4; ++ni)
                        acc[mi][ni] = __builtin_amdgcn_mfma_f32_16x16x32_bf16(af[mi], bf[ni], acc[mi][ni], 0, 0, 0);
            }
            __syncthreads();   // drains vmcnt (next stage landed) + guards buf reuse
            cur ^= 1;
        }
#pragma unroll
        for (int ni = 0; ni < 4; ni++) {
            int col = n0 + wc * 64 + ni * 16 + lc;
            float bv = bq[col];
#pragma unroll
            for (int mi = 0; mi < 4; mi++) {
                int r0 = wr * 64 + mi * 16 + lr * 4;
                int bb = r0 >> 3;
                int t0 = 8 * m + (r0 & 7);
                float4 st = { acc[mi][ni][0] + bv, acc[mi][ni][1] + bv,
                              acc[mi][ni][2] + bv, acc[mi][ni][3] + bv };
                *(float4*)(out + (size_t)bb * 4096000 + (size_t)col * 128 + t0) = st;
            }
        }
    }
}

extern "C" void kernel_launch(void* const* d_in, const int* in_sizes, int n_in,
                              void* d_out, int out_size, void* d_ws, size_t ws_size,
                              hipStream_t stream) {
    const int*   sent = (const int*)d_in[0];
    const float* emb  = (const float*)d_in[1];
    const float* W_i  = (const float*)d_in[2];
    const float* b_i  = (const float*)d_in[3];
    const float* W_f  = (const float*)d_in[4];
    const float* b_f  = (const float*)d_in[5];
    const float* W_o  = (const float*)d_in[6];
    const float* b_o  = (const float*)d_in[7];
    const float* W_c  = (const float*)d_in[8];
    const float* b_c  = (const float*)d_in[9];
    const float* W_hq = (const float*)d_in[10];
    const float* b_q  = (const float*)d_in[11];
    float* out = (float*)d_out;

    char* ws = (char*)d_ws;
    size_t off = 0;
    auto alloc = [&](size_t bytes) { void* p = ws + off; off += (bytes + 255) & ~255ull; return p; };
    u32*   flags = (u32*)alloc((size_t)FLAG_WORDS * 4);
    u16*   xb   = (u16*)alloc((size_t)2048 * 512 * 2);
    u16*   hs   = (u16*)alloc((size_t)2048 * 1024 * 2);
    u16*   whqt = (u16*)alloc((size_t)32000 * 1024 * 2);

    hipMemsetAsync(flags, 0, (size_t)FLAG_WORDS * 4, stream);
    // prep: embedding gather only
    prep<<<1024, 256, 0, stream>>>(sent, emb, xb);
    // fused: 64 lstm blocks (role-split waves) + 192 proj workers
    lstm_proj<<<256, 512, 0, stream>>>(hs, xb, W_i, W_f, W_o, W_c,
                                       b_i, b_f, b_o, b_c,
                                       flags, W_hq, whqt, b_q, out);
}